// Round 2
// baseline (610.928 us; speedup 1.0000x reference)
//
#include <hip/hip_runtime.h>

typedef short s16x8 __attribute__((ext_vector_type(8)));
typedef float f32x4 __attribute__((ext_vector_type(4)));
typedef unsigned short u16x4v __attribute__((ext_vector_type(4)));

#define NEGF (-1e30f)

// B=8, N=2048, all feature dims 128. Inputs/outputs are float32 (per the
// reference's jnp.float32); internal pipeline is bf16 MFMA (2%-of-max budget).

__device__ __forceinline__ float bf2f(unsigned short u) {
  union { unsigned int i; float f; } v; v.i = ((unsigned int)u) << 16; return v.f;
}
__device__ __forceinline__ unsigned short f2bf(float f) {
  union { float fl; unsigned int i; } v; v.fl = f;
  unsigned int x = v.i;
  x += 0x7fffu + ((x >> 16) & 1u);   // round-to-nearest-even
  return (unsigned short)(x >> 16);
}
__device__ __forceinline__ s16x8 load8_bf16(const unsigned short* p) {
  return *(const s16x8*)p;
}
__device__ __forceinline__ s16x8 load8_f32(const float* p) {
  float4 a = *(const float4*)p;
  float4 b = *(const float4*)(p + 4);
  s16x8 r;
  r[0] = (short)f2bf(a.x); r[1] = (short)f2bf(a.y);
  r[2] = (short)f2bf(a.z); r[3] = (short)f2bf(a.w);
  r[4] = (short)f2bf(b.x); r[5] = (short)f2bf(b.y);
  r[6] = (short)f2bf(b.z); r[7] = (short)f2bf(b.w);
  return r;
}

// ---------------------------------------------------------------------------
// Weight/bias f32 -> bf16 conversion into workspace. blockIdx.y selects tensor.
// ---------------------------------------------------------------------------
#define OW_Q1 0
#define OW_K1 16384
#define OW_V1 32768
#define OW_O1 49152
#define OW_Q2 65536
#define OW_K2 81920
#define OW_V2 98304
#define OW_O2 114688
#define OW_F  131072        // 128x256
#define OB_Q1 163840
#define OB_K1 163968
#define OB_V1 164096
#define OB_O1 164224
#define OB_Q2 164352
#define OB_K2 164480
#define OB_V2 164608
#define OB_O2 164736
#define OB_F  164864
#define WBF_ELEMS 165120    // rounded up, keeps mask base 8B-aligned

__global__ __launch_bounds__(256) void conv_w_kernel(
    const float* s0, const float* s1, const float* s2, const float* s3,
    const float* s4, const float* s5, const float* s6, const float* s7,
    const float* s8, const float* s9, const float* s10, const float* s11,
    const float* s12, const float* s13, const float* s14, const float* s15,
    const float* s16, const float* s17, unsigned short* dst)
{
  const float* src; int count; int off;
  switch (blockIdx.y) {
    case 0:  src = s0;  count = 16384; off = OW_Q1; break;
    case 1:  src = s1;  count = 16384; off = OW_K1; break;
    case 2:  src = s2;  count = 16384; off = OW_V1; break;
    case 3:  src = s3;  count = 16384; off = OW_O1; break;
    case 4:  src = s4;  count = 16384; off = OW_Q2; break;
    case 5:  src = s5;  count = 16384; off = OW_K2; break;
    case 6:  src = s6;  count = 16384; off = OW_V2; break;
    case 7:  src = s7;  count = 16384; off = OW_O2; break;
    case 8:  src = s8;  count = 32768; off = OW_F;  break;
    case 9:  src = s9;  count = 128;   off = OB_Q1; break;
    case 10: src = s10; count = 128;   off = OB_K1; break;
    case 11: src = s11; count = 128;   off = OB_V1; break;
    case 12: src = s12; count = 128;   off = OB_O1; break;
    case 13: src = s13; count = 128;   off = OB_Q2; break;
    case 14: src = s14; count = 128;   off = OB_K2; break;
    case 15: src = s15; count = 128;   off = OB_V2; break;
    case 16: src = s16; count = 128;   off = OB_O2; break;
    default: src = s17; count = 128;   off = OB_F;  break;
  }
  for (int i = blockIdx.x * 256 + threadIdx.x; i < count; i += gridDim.x * 256)
    dst[off + i] = f2bf(src[i]);
}

// ---------------------------------------------------------------------------
// adj (f32 0.0/1.0, [B,2048,2048]) -> bitmask u64 per (row, 64-key chunk).
// Exactly 8*2048*2048 threads; each wave ballots 64 consecutive keys.
// ---------------------------------------------------------------------------
__global__ __launch_bounds__(256) void pack_adj_kernel(
    const float* __restrict__ adj, unsigned long long* __restrict__ mask)
{
  const size_t i = (size_t)blockIdx.x * 256 + threadIdx.x;
  unsigned long long m = __ballot(adj[i] != 0.0f);
  if ((threadIdx.x & 63) == 0) mask[i >> 6] = m;
}

// ---------------------------------------------------------------------------
// NT GEMM body, M tiled 64/wg (16/wave), N=128, K=128 (x2 if DUAL).
// A1 is f32 or bf16 (template); A2 (DUAL) is f32. W/bias always bf16 (ws).
// MODE 0: bf16 rowmajor out[m*128+n]; MODE 1: bf16 transposed
// out[(b*128+n)*2048 + m%2048]; MODE 2: f32 rowmajor.
// ---------------------------------------------------------------------------
template <bool A1F32, bool DUAL, bool RELU, int MODE>
__device__ __forceinline__ void gemm_body(
    const void* __restrict__ A1, const unsigned short* __restrict__ W1, int ws1,
    const float* __restrict__ A2, const unsigned short* __restrict__ W2, int ws2,
    const unsigned short* __restrict__ bias, void* __restrict__ outp)
{
  const int t = threadIdx.x;
  const int w = t >> 6;
  const int lane = t & 63;
  const int l15 = lane & 15;
  const int quad = lane >> 4;
  const int mbase = blockIdx.x * 64 + w * 16;

  s16x8 a1[4], a2[4];
  if (A1F32) {
    const float* ar = (const float*)A1 + (size_t)(mbase + l15) * 128;
#pragma unroll
    for (int ks = 0; ks < 4; ++ks) a1[ks] = load8_f32(ar + ks * 32 + quad * 8);
  } else {
    const unsigned short* ar = (const unsigned short*)A1 + (size_t)(mbase + l15) * 128;
#pragma unroll
    for (int ks = 0; ks < 4; ++ks) a1[ks] = load8_bf16(ar + ks * 32 + quad * 8);
  }
  if (DUAL) {
    const float* ar = A2 + (size_t)(mbase + l15) * 128;
#pragma unroll
    for (int ks = 0; ks < 4; ++ks) a2[ks] = load8_f32(ar + ks * 32 + quad * 8);
  }

#pragma unroll
  for (int nt = 0; nt < 8; ++nt) {
    const int n = nt * 16 + l15;
    f32x4 acc = {0.f, 0.f, 0.f, 0.f};
    {
      const unsigned short* wr = W1 + (size_t)n * ws1;
#pragma unroll
      for (int ks = 0; ks < 4; ++ks)
        acc = __builtin_amdgcn_mfma_f32_16x16x32_bf16(
            a1[ks], load8_bf16(wr + ks * 32 + quad * 8), acc, 0, 0, 0);
    }
    if (DUAL) {
      const unsigned short* wr = W2 + (size_t)n * ws2;
#pragma unroll
      for (int ks = 0; ks < 4; ++ks)
        acc = __builtin_amdgcn_mfma_f32_16x16x32_bf16(
            a2[ks], load8_bf16(wr + ks * 32 + quad * 8), acc, 0, 0, 0);
    }
    const float bv = bf2f(bias[n]);
    if (MODE == 0) {
      unsigned short* out = (unsigned short*)outp;
#pragma unroll
      for (int r = 0; r < 4; ++r) {
        float v = acc[r] + bv;
        if (RELU) v = fmaxf(v, 0.f);
        // C layout: row = quad*4+r (M), col = n (N)  [m89-verified]
        out[(size_t)(mbase + quad * 4 + r) * 128 + n] = f2bf(v);
      }
    } else if (MODE == 1) {
      unsigned short* out = (unsigned short*)outp;
      const int b  = mbase >> 11;
      const int nn = (mbase & 2047) + quad * 4;
      u16x4v pk;
#pragma unroll
      for (int r = 0; r < 4; ++r) {
        float v = acc[r] + bv;
        if (RELU) v = fmaxf(v, 0.f);
        pk[r] = f2bf(v);
      }
      *(u16x4v*)(out + (size_t)(b * 128 + n) * 2048 + nn) = pk;
    } else {
      float* out = (float*)outp;
#pragma unroll
      for (int r = 0; r < 4; ++r) {
        float v = acc[r] + bv;
        if (RELU) v = fmaxf(v, 0.f);
        out[(size_t)(mbase + quad * 4 + r) * 128 + n] = v;
      }
    }
  }
}

template <bool A1F32>
__global__ __launch_bounds__(256) void qkv_kernel(
    const void* __restrict__ x,
    const unsigned short* __restrict__ Wq, const unsigned short* __restrict__ bq, unsigned short* __restrict__ oq,
    const unsigned short* __restrict__ Wk, const unsigned short* __restrict__ bk, unsigned short* __restrict__ ok,
    const unsigned short* __restrict__ Wv, const unsigned short* __restrict__ bv, unsigned short* __restrict__ ovt)
{
  if (blockIdx.y == 0)
    gemm_body<A1F32, false, true, 0>(x, Wq, 128, nullptr, nullptr, 0, bq, oq);
  else if (blockIdx.y == 1)
    gemm_body<A1F32, false, true, 0>(x, Wk, 128, nullptr, nullptr, 0, bk, ok);
  else
    gemm_body<A1F32, false, true, 1>(x, Wv, 128, nullptr, nullptr, 0, bv, ovt);
}

__global__ __launch_bounds__(256) void lin_kernel(
    const unsigned short* __restrict__ x,
    const unsigned short* __restrict__ W, const unsigned short* __restrict__ b,
    unsigned short* __restrict__ out)
{
  gemm_body<false, false, false, 0>(x, W, 128, nullptr, nullptr, 0, b, out);
}

__global__ __launch_bounds__(256) void final_kernel(
    const unsigned short* __restrict__ f2,
    const unsigned short* __restrict__ Wf,    // bf16 copy, row stride 256
    const float* __restrict__ vae2,
    const unsigned short* __restrict__ bfb,
    float* __restrict__ out)
{
  gemm_body<false, true, false, 2>(f2, Wf, 256, vae2, Wf + 128, 256, bfb, out);
}

// ---------------------------------------------------------------------------
// Flash-style masked attention; Q,K bf16 [B*2048,128]; VT bf16 [B*128,2048];
// MASK u64 [B,2048,32]. 1 wg = 4 waves = 64 Q rows, K-chunks of 64.
// ---------------------------------------------------------------------------
__global__ __launch_bounds__(256) void attn_kernel(
    const unsigned short* __restrict__ Q,
    const unsigned short* __restrict__ K,
    const unsigned short* __restrict__ VT,
    const unsigned long long* __restrict__ MASK,
    unsigned short* __restrict__ O)
{
  __shared__ __align__(16) unsigned short kbuf[64][136];
  __shared__ __align__(16) unsigned short vbuf[128][72];
  __shared__ __align__(16) unsigned short pbuf[4][16][72];

  const int t = threadIdx.x;
  const int w = t >> 6;
  const int lane = t & 63;
  const int l15 = lane & 15;
  const int quad = lane >> 4;

  const int gq0 = blockIdx.x * 64;
  const int b   = gq0 >> 11;
  const int q0  = gq0 & 2047;
  const int wq0 = q0 + w * 16;

  s16x8 qf[4];
  {
    const unsigned short* qrow = Q + (size_t)(gq0 + w * 16 + l15) * 128;
#pragma unroll
    for (int ks = 0; ks < 4; ++ks) qf[ks] = load8_bf16(qrow + ks * 32 + quad * 8);
  }

  float mstate[4], lstate[4];
  f32x4 accO[8];
#pragma unroll
  for (int r = 0; r < 4; ++r) { mstate[r] = NEGF; lstate[r] = 0.f; }
#pragma unroll
  for (int dt = 0; dt < 8; ++dt) accO[dt] = (f32x4){0.f, 0.f, 0.f, 0.f};

  const unsigned short* Kb  = K  + (size_t)(b * 2048) * 128;
  const unsigned short* VTb = VT + (size_t)(b * 128) * 2048;
  const unsigned long long* Mb = MASK + (size_t)b * 2048 * 32;

  for (int kc = 0; kc < 2048; kc += 64) {
    __syncthreads();
#pragma unroll
    for (int i = 0; i < 4; ++i) {
      int slot = i * 256 + t;
      int row = slot >> 4, c8 = (slot & 15) * 8;
      *(s16x8*)&kbuf[row][c8] = load8_bf16(Kb + (size_t)(kc + row) * 128 + c8);
    }
#pragma unroll
    for (int i = 0; i < 4; ++i) {
      int slot = i * 256 + t;
      int row = slot >> 3, c8 = (slot & 7) * 8;
      *(s16x8*)&vbuf[row][c8] = load8_bf16(VTb + (size_t)row * 2048 + kc + c8);
    }
    __syncthreads();

    f32x4 sv[4];
#pragma unroll
    for (int nt = 0; nt < 4; ++nt) {
      f32x4 acc = {0.f, 0.f, 0.f, 0.f};
#pragma unroll
      for (int ks = 0; ks < 4; ++ks) {
        s16x8 kf = *(const s16x8*)&kbuf[nt * 16 + l15][ks * 32 + quad * 8];
        acc = __builtin_amdgcn_mfma_f32_16x16x32_bf16(qf[ks], kf, acc, 0, 0, 0);
      }
      sv[nt] = acc;
    }

    unsigned long long mw[4];
#pragma unroll
    for (int r = 0; r < 4; ++r)
      mw[r] = Mb[(size_t)(wq0 + quad * 4 + r) * 32 + (kc >> 6)];

    float chmax[4] = {NEGF, NEGF, NEGF, NEGF};
#pragma unroll
    for (int nt = 0; nt < 4; ++nt) {
#pragma unroll
      for (int r = 0; r < 4; ++r) {
        float s = ((mw[r] >> (nt * 16 + l15)) & 1ull) ? sv[nt][r] : NEGF;
        sv[nt][r] = s;
        chmax[r] = fmaxf(chmax[r], s);
      }
    }
#pragma unroll
    for (int d = 1; d < 16; d <<= 1) {
#pragma unroll
      for (int r = 0; r < 4; ++r)
        chmax[r] = fmaxf(chmax[r], __shfl_xor(chmax[r], d, 64));
    }

    float mnew[4], alpha[4], rsum[4];
#pragma unroll
    for (int r = 0; r < 4; ++r) {
      mnew[r] = fmaxf(mstate[r], chmax[r]);
      alpha[r] = __expf(mstate[r] - mnew[r]);  // NEG-NEG -> 1, NEG-real -> 0
      rsum[r] = 0.f;
    }
#pragma unroll
    for (int nt = 0; nt < 4; ++nt) {
#pragma unroll
      for (int r = 0; r < 4; ++r) {
        float p = __expf(sv[nt][r] - mnew[r]);
        rsum[r] += p;
        pbuf[w][quad * 4 + r][nt * 16 + l15] = f2bf(p);
      }
    }
#pragma unroll
    for (int d = 1; d < 16; d <<= 1) {
#pragma unroll
      for (int r = 0; r < 4; ++r)
        rsum[r] += __shfl_xor(rsum[r], d, 64);
    }
#pragma unroll
    for (int r = 0; r < 4; ++r) {
      lstate[r] = lstate[r] * alpha[r] + rsum[r];
      mstate[r] = mnew[r];
    }
#pragma unroll
    for (int dt = 0; dt < 8; ++dt) {
#pragma unroll
      for (int r = 0; r < 4; ++r) accO[dt][r] *= alpha[r];
    }

    __syncthreads();

    s16x8 pf[2];
#pragma unroll
    for (int ks = 0; ks < 2; ++ks)
      pf[ks] = *(const s16x8*)&pbuf[w][l15][ks * 32 + quad * 8];
#pragma unroll
    for (int dt = 0; dt < 8; ++dt) {
      f32x4 acc = accO[dt];
#pragma unroll
      for (int ks = 0; ks < 2; ++ks) {
        s16x8 vf = *(const s16x8*)&vbuf[dt * 16 + l15][ks * 32 + quad * 8];
        acc = __builtin_amdgcn_mfma_f32_16x16x32_bf16(pf[ks], vf, acc, 0, 0, 0);
      }
      accO[dt] = acc;
    }
  }

  float inv[4];
#pragma unroll
  for (int r = 0; r < 4; ++r) inv[r] = (lstate[r] > 0.f) ? 1.f / lstate[r] : 0.f;
#pragma unroll
  for (int dt = 0; dt < 8; ++dt) {
    int dcol = dt * 16 + l15;
#pragma unroll
    for (int r = 0; r < 4; ++r) {
      int qg = gq0 + w * 16 + quad * 4 + r;
      O[(size_t)qg * 128 + dcol] = f2bf(accO[dt][r] * inv[r]);
    }
  }
}

extern "C" void kernel_launch(void* const* d_in, const int* in_sizes, int n_in,
                              void* d_out, int out_size, void* d_ws, size_t ws_size,
                              hipStream_t stream)
{
  const float* h    = (const float*)d_in[0];
  const float* adj  = (const float*)d_in[1];
  const float* vae2 = (const float*)d_in[2];
  const float* Wv1  = (const float*)d_in[3];
  const float* bv1  = (const float*)d_in[4];
  const float* Wk1  = (const float*)d_in[5];
  const float* bk1  = (const float*)d_in[6];
  const float* Wq1  = (const float*)d_in[7];
  const float* bq1  = (const float*)d_in[8];
  const float* Wo1  = (const float*)d_in[9];
  const float* bo1  = (const float*)d_in[10];
  const float* Wv2  = (const float*)d_in[11];
  const float* bv2  = (const float*)d_in[12];
  const float* Wk2  = (const float*)d_in[13];
  const float* bk2  = (const float*)d_in[14];
  const float* Wq2  = (const float*)d_in[15];
  const float* bq2  = (const float*)d_in[16];
  const float* Wo2  = (const float*)d_in[17];
  const float* bo2  = (const float*)d_in[18];
  const float* Wf   = (const float*)d_in[19];
  const float* bff  = (const float*)d_in[20];

  unsigned short* ws = (unsigned short*)d_ws;
  const size_t SLOT = (size_t)16384 * 128;
  unsigned short* s_q  = ws;
  unsigned short* s_k  = ws + SLOT;
  unsigned short* s_vt = ws + 2 * SLOT;
  unsigned short* s_a  = ws + 3 * SLOT;
  unsigned short* s_f  = ws + 4 * SLOT;
  unsigned short* wbf  = ws + 5 * SLOT;
  unsigned long long* maskp = (unsigned long long*)(ws + 5 * SLOT + WBF_ELEMS);

  dim3 blk(256);
  conv_w_kernel<<<dim3(128, 18), blk, 0, stream>>>(
      Wq1, Wk1, Wv1, Wo1, Wq2, Wk2, Wv2, Wo2, Wf,
      bq1, bk1, bv1, bo1, bq2, bk2, bv2, bo2, bff, wbf);
  pack_adj_kernel<<<dim3(131072), blk, 0, stream>>>(adj, maskp);

  qkv_kernel<true><<<dim3(256, 3), blk, 0, stream>>>(
      h, wbf + OW_Q1, wbf + OB_Q1, s_q,
         wbf + OW_K1, wbf + OB_K1, s_k,
         wbf + OW_V1, wbf + OB_V1, s_vt);
  attn_kernel<<<dim3(256), blk, 0, stream>>>(s_q, s_k, s_vt, maskp, s_a);
  lin_kernel<<<dim3(256), blk, 0, stream>>>(s_a, wbf + OW_O1, wbf + OB_O1, s_f);

  qkv_kernel<false><<<dim3(256, 3), blk, 0, stream>>>(
      s_f, wbf + OW_Q2, wbf + OB_Q2, s_q,
           wbf + OW_K2, wbf + OB_K2, s_k,
           wbf + OW_V2, wbf + OB_V2, s_vt);
  attn_kernel<<<dim3(256), blk, 0, stream>>>(s_q, s_k, s_vt, maskp, s_a);
  lin_kernel<<<dim3(256), blk, 0, stream>>>(s_a, wbf + OW_O2, wbf + OB_O2, s_f);

  final_kernel<<<dim3(256), blk, 0, stream>>>(
      s_f, wbf + OW_F, vae2, wbf + OB_F, (float*)d_out);
}

// Round 3
// 512.833 us; speedup vs baseline: 1.1913x; 1.1913x over previous
//
#include <hip/hip_runtime.h>

typedef short s16x8 __attribute__((ext_vector_type(8)));
typedef float f32x4 __attribute__((ext_vector_type(4)));
typedef unsigned short u16x4v __attribute__((ext_vector_type(4)));

#define NEGF (-1e30f)
#define NSPLIT 4
#define NROWS 16384   // B*N

__device__ __forceinline__ float bf2f(unsigned short u) {
  union { unsigned int i; float f; } v; v.i = ((unsigned int)u) << 16; return v.f;
}
__device__ __forceinline__ unsigned short f2bf(float f) {
  union { float fl; unsigned int i; } v; v.fl = f;
  unsigned int x = v.i;
  x += 0x7fffu + ((x >> 16) & 1u);   // round-to-nearest-even
  return (unsigned short)(x >> 16);
}
__device__ __forceinline__ s16x8 load8_bf16(const unsigned short* p) {
  return *(const s16x8*)p;
}
__device__ __forceinline__ s16x8 load8_f32(const float* p) {
  float4 a = *(const float4*)p;
  float4 b = *(const float4*)(p + 4);
  s16x8 r;
  r[0] = (short)f2bf(a.x); r[1] = (short)f2bf(a.y);
  r[2] = (short)f2bf(a.z); r[3] = (short)f2bf(a.w);
  r[4] = (short)f2bf(b.x); r[5] = (short)f2bf(b.y);
  r[6] = (short)f2bf(b.z); r[7] = (short)f2bf(b.w);
  return r;
}

// ---------------------------------------------------------------------------
// Weight/bias f32 -> bf16 conversion into workspace (element offsets).
// ---------------------------------------------------------------------------
#define OW_Q1 0
#define OW_K1 16384
#define OW_V1 32768
#define OW_O1 49152
#define OW_Q2 65536
#define OW_K2 81920
#define OW_V2 98304
#define OW_O2 114688
#define OW_F  131072        // 128x256
#define OB_Q1 163840
#define OB_K1 163968
#define OB_V1 164096
#define OB_O1 164224
#define OB_Q2 164352
#define OB_K2 164480
#define OB_V2 164608
#define OB_O2 164736
#define OB_F  164864

__global__ __launch_bounds__(256) void conv_w_kernel(
    const float* s0, const float* s1, const float* s2, const float* s3,
    const float* s4, const float* s5, const float* s6, const float* s7,
    const float* s8, const float* s9, const float* s10, const float* s11,
    const float* s12, const float* s13, const float* s14, const float* s15,
    const float* s16, const float* s17, unsigned short* dst)
{
  const float* src; int count; int off;
  switch (blockIdx.y) {
    case 0:  src = s0;  count = 16384; off = OW_Q1; break;
    case 1:  src = s1;  count = 16384; off = OW_K1; break;
    case 2:  src = s2;  count = 16384; off = OW_V1; break;
    case 3:  src = s3;  count = 16384; off = OW_O1; break;
    case 4:  src = s4;  count = 16384; off = OW_Q2; break;
    case 5:  src = s5;  count = 16384; off = OW_K2; break;
    case 6:  src = s6;  count = 16384; off = OW_V2; break;
    case 7:  src = s7;  count = 16384; off = OW_O2; break;
    case 8:  src = s8;  count = 32768; off = OW_F;  break;
    case 9:  src = s9;  count = 128;   off = OB_Q1; break;
    case 10: src = s10; count = 128;   off = OB_K1; break;
    case 11: src = s11; count = 128;   off = OB_V1; break;
    case 12: src = s12; count = 128;   off = OB_O1; break;
    case 13: src = s13; count = 128;   off = OB_Q2; break;
    case 14: src = s14; count = 128;   off = OB_K2; break;
    case 15: src = s15; count = 128;   off = OB_V2; break;
    case 16: src = s16; count = 128;   off = OB_O2; break;
    default: src = s17; count = 128;   off = OB_F;  break;
  }
  for (int i = blockIdx.x * 256 + threadIdx.x; i < count; i += gridDim.x * 256)
    dst[off + i] = f2bf(src[i]);
}

// ---------------------------------------------------------------------------
// adj (f32 0/1, [B,2048,2048]) -> u64 bitmask per (row, 64-key chunk).
// ---------------------------------------------------------------------------
__global__ __launch_bounds__(256) void pack_adj_kernel(
    const float* __restrict__ adj, unsigned long long* __restrict__ mask)
{
  const size_t i = (size_t)blockIdx.x * 256 + threadIdx.x;
  unsigned long long m = __ballot(adj[i] != 0.0f);
  if ((threadIdx.x & 63) == 0) mask[i >> 6] = m;
}

// ---------------------------------------------------------------------------
// NT GEMM: wg = 16 rows x 128 cols; wave w owns cols [w*32, w*32+32).
// grid.x = M/16 = 1024 -> 4096 waves (occupancy fix vs round 2's 1024).
// MODE 0: bf16 rowmajor; MODE 1: bf16 transposed (V^T); MODE 2: f32 rowmajor.
// ---------------------------------------------------------------------------
template <bool A1F32, bool DUAL, bool RELU, int MODE>
__device__ __forceinline__ void gemm_body(
    const void* __restrict__ A1, const unsigned short* __restrict__ W1, int ws1,
    const float* __restrict__ A2, const unsigned short* __restrict__ W2, int ws2,
    const unsigned short* __restrict__ bias, void* __restrict__ outp)
{
  const int t = threadIdx.x;
  const int w = t >> 6;
  const int lane = t & 63;
  const int l15 = lane & 15;
  const int quad = lane >> 4;
  const int mbase = blockIdx.x * 16;

  s16x8 a1[4], a2[4];
  if (A1F32) {
    const float* ar = (const float*)A1 + (size_t)(mbase + l15) * 128;
#pragma unroll
    for (int ks = 0; ks < 4; ++ks) a1[ks] = load8_f32(ar + ks * 32 + quad * 8);
  } else {
    const unsigned short* ar = (const unsigned short*)A1 + (size_t)(mbase + l15) * 128;
#pragma unroll
    for (int ks = 0; ks < 4; ++ks) a1[ks] = load8_bf16(ar + ks * 32 + quad * 8);
  }
  if (DUAL) {
    const float* ar = A2 + (size_t)(mbase + l15) * 128;
#pragma unroll
    for (int ks = 0; ks < 4; ++ks) a2[ks] = load8_f32(ar + ks * 32 + quad * 8);
  }

#pragma unroll
  for (int nt = 0; nt < 2; ++nt) {
    const int n = (w * 2 + nt) * 16 + l15;
    f32x4 acc = {0.f, 0.f, 0.f, 0.f};
    {
      const unsigned short* wr = W1 + (size_t)n * ws1;
#pragma unroll
      for (int ks = 0; ks < 4; ++ks)
        acc = __builtin_amdgcn_mfma_f32_16x16x32_bf16(
            a1[ks], load8_bf16(wr + ks * 32 + quad * 8), acc, 0, 0, 0);
    }
    if (DUAL) {
      const unsigned short* wr = W2 + (size_t)n * ws2;
#pragma unroll
      for (int ks = 0; ks < 4; ++ks)
        acc = __builtin_amdgcn_mfma_f32_16x16x32_bf16(
            a2[ks], load8_bf16(wr + ks * 32 + quad * 8), acc, 0, 0, 0);
    }
    const float bv = bf2f(bias[n]);
    if (MODE == 0) {
      unsigned short* out = (unsigned short*)outp;
#pragma unroll
      for (int r = 0; r < 4; ++r) {
        float v = acc[r] + bv;
        if (RELU) v = fmaxf(v, 0.f);
        // C layout: row = quad*4+r (M), col = n (N)  [m89-verified]
        out[(size_t)(mbase + quad * 4 + r) * 128 + n] = f2bf(v);
      }
    } else if (MODE == 1) {
      unsigned short* out = (unsigned short*)outp;
      const int b  = mbase >> 11;
      const int nn = (mbase & 2047) + quad * 4;
      u16x4v pk;
#pragma unroll
      for (int r = 0; r < 4; ++r) {
        float v = acc[r] + bv;
        if (RELU) v = fmaxf(v, 0.f);
        pk[r] = f2bf(v);
      }
      *(u16x4v*)(out + (size_t)(b * 128 + n) * 2048 + nn) = pk;
    } else {
      float* out = (float*)outp;
#pragma unroll
      for (int r = 0; r < 4; ++r) {
        float v = acc[r] + bv;
        if (RELU) v = fmaxf(v, 0.f);
        out[(size_t)(mbase + quad * 4 + r) * 128 + n] = v;
      }
    }
  }
}

template <bool A1F32>
__global__ __launch_bounds__(256) void qkv_kernel(
    const void* __restrict__ x,
    const unsigned short* __restrict__ Wq, const unsigned short* __restrict__ bq, unsigned short* __restrict__ oq,
    const unsigned short* __restrict__ Wk, const unsigned short* __restrict__ bk, unsigned short* __restrict__ ok,
    const unsigned short* __restrict__ Wv, const unsigned short* __restrict__ bv, unsigned short* __restrict__ ovt)
{
  if (blockIdx.y == 0)
    gemm_body<A1F32, false, true, 0>(x, Wq, 128, nullptr, nullptr, 0, bq, oq);
  else if (blockIdx.y == 1)
    gemm_body<A1F32, false, true, 0>(x, Wk, 128, nullptr, nullptr, 0, bk, ok);
  else
    gemm_body<A1F32, false, true, 1>(x, Wv, 128, nullptr, nullptr, 0, bv, ovt);
}

__global__ __launch_bounds__(256) void lin_kernel(
    const unsigned short* __restrict__ x,
    const unsigned short* __restrict__ W, const unsigned short* __restrict__ b,
    unsigned short* __restrict__ out)
{
  gemm_body<false, false, false, 0>(x, W, 128, nullptr, nullptr, 0, b, out);
}

__global__ __launch_bounds__(256) void final_kernel(
    const unsigned short* __restrict__ f2,
    const unsigned short* __restrict__ Wf,    // bf16, row stride 256
    const float* __restrict__ vae2,
    const unsigned short* __restrict__ bfb,
    float* __restrict__ out)
{
  gemm_body<false, true, false, 2>(f2, Wf, 256, vae2, Wf + 128, 256, bfb, out);
}

// ---------------------------------------------------------------------------
// Split-K flash attention. grid = (256 row-blocks, NSPLIT). Each split handles
// 2048/NSPLIT keys and writes unnormalized partial O (f32) + per-row (m,l).
// ---------------------------------------------------------------------------
__global__ __launch_bounds__(256) void attn_kernel(
    const unsigned short* __restrict__ Q,
    const unsigned short* __restrict__ K,
    const unsigned short* __restrict__ VT,
    const unsigned long long* __restrict__ MASK,
    float* __restrict__ pO, float* __restrict__ pm, float* __restrict__ pl)
{
  __shared__ __align__(16) unsigned short kbuf[64][136];
  __shared__ __align__(16) unsigned short vbuf[128][72];
  __shared__ __align__(16) unsigned short pbuf[4][16][72];

  const int t = threadIdx.x;
  const int w = t >> 6;
  const int lane = t & 63;
  const int l15 = lane & 15;
  const int quad = lane >> 4;

  const int gq0 = blockIdx.x * 64;
  const int b   = gq0 >> 11;
  const int q0  = gq0 & 2047;
  const int wq0 = q0 + w * 16;
  const int split = blockIdx.y;
  const int kc0 = split * (2048 / NSPLIT);
  const int kc1 = kc0 + (2048 / NSPLIT);

  s16x8 qf[4];
  {
    const unsigned short* qrow = Q + (size_t)(gq0 + w * 16 + l15) * 128;
#pragma unroll
    for (int ks = 0; ks < 4; ++ks) qf[ks] = load8_bf16(qrow + ks * 32 + quad * 8);
  }

  float mstate[4], lstate[4];
  f32x4 accO[8];
#pragma unroll
  for (int r = 0; r < 4; ++r) { mstate[r] = NEGF; lstate[r] = 0.f; }
#pragma unroll
  for (int dt = 0; dt < 8; ++dt) accO[dt] = (f32x4){0.f, 0.f, 0.f, 0.f};

  const unsigned short* Kb  = K  + (size_t)(b * 2048) * 128;
  const unsigned short* VTb = VT + (size_t)(b * 128) * 2048;
  const unsigned long long* Mb = MASK + (size_t)b * 2048 * 32;

  for (int kc = kc0; kc < kc1; kc += 64) {
    __syncthreads();   // prior chunk's LDS reads done before overwrite
#pragma unroll
    for (int i = 0; i < 4; ++i) {
      int slot = i * 256 + t;
      int row = slot >> 4, c8 = (slot & 15) * 8;
      *(s16x8*)&kbuf[row][c8] = load8_bf16(Kb + (size_t)(kc + row) * 128 + c8);
    }
#pragma unroll
    for (int i = 0; i < 4; ++i) {
      int slot = i * 256 + t;
      int row = slot >> 3, c8 = (slot & 7) * 8;
      *(s16x8*)&vbuf[row][c8] = load8_bf16(VTb + (size_t)row * 2048 + kc + c8);
    }
    __syncthreads();

    f32x4 sv[4];
#pragma unroll
    for (int nt = 0; nt < 4; ++nt) {
      f32x4 acc = {0.f, 0.f, 0.f, 0.f};
#pragma unroll
      for (int ks = 0; ks < 4; ++ks) {
        s16x8 kf = *(const s16x8*)&kbuf[nt * 16 + l15][ks * 32 + quad * 8];
        acc = __builtin_amdgcn_mfma_f32_16x16x32_bf16(qf[ks], kf, acc, 0, 0, 0);
      }
      sv[nt] = acc;
    }

    unsigned long long mw[4];
#pragma unroll
    for (int r = 0; r < 4; ++r)
      mw[r] = Mb[(size_t)(wq0 + quad * 4 + r) * 32 + (kc >> 6)];

    float chmax[4] = {NEGF, NEGF, NEGF, NEGF};
#pragma unroll
    for (int nt = 0; nt < 4; ++nt) {
#pragma unroll
      for (int r = 0; r < 4; ++r) {
        float s = ((mw[r] >> (nt * 16 + l15)) & 1ull) ? sv[nt][r] : NEGF;
        sv[nt][r] = s;
        chmax[r] = fmaxf(chmax[r], s);
      }
    }
#pragma unroll
    for (int d = 1; d < 16; d <<= 1) {
#pragma unroll
      for (int r = 0; r < 4; ++r)
        chmax[r] = fmaxf(chmax[r], __shfl_xor(chmax[r], d, 64));
    }

    float mnew[4], alpha[4], rsum[4];
#pragma unroll
    for (int r = 0; r < 4; ++r) {
      mnew[r] = fmaxf(mstate[r], chmax[r]);
      alpha[r] = __expf(mstate[r] - mnew[r]);  // NEG-NEG -> 1, NEG-real -> 0
      rsum[r] = 0.f;
    }
#pragma unroll
    for (int nt = 0; nt < 4; ++nt) {
#pragma unroll
      for (int r = 0; r < 4; ++r) {
        float p = __expf(sv[nt][r] - mnew[r]);
        rsum[r] += p;
        pbuf[w][quad * 4 + r][nt * 16 + l15] = f2bf(p);
      }
    }
#pragma unroll
    for (int d = 1; d < 16; d <<= 1) {
#pragma unroll
      for (int r = 0; r < 4; ++r)
        rsum[r] += __shfl_xor(rsum[r], d, 64);
    }
#pragma unroll
    for (int r = 0; r < 4; ++r) {
      lstate[r] = lstate[r] * alpha[r] + rsum[r];
      mstate[r] = mnew[r];
    }
#pragma unroll
    for (int dt = 0; dt < 8; ++dt) {
#pragma unroll
      for (int r = 0; r < 4; ++r) accO[dt][r] *= alpha[r];
    }

    // pbuf is wave-local: in-wave LDS RAW is lgkmcnt-ordered, no barrier.
    s16x8 pf[2];
#pragma unroll
    for (int ks = 0; ks < 2; ++ks)
      pf[ks] = *(const s16x8*)&pbuf[w][l15][ks * 32 + quad * 8];
#pragma unroll
    for (int dt = 0; dt < 8; ++dt) {
      f32x4 acc = accO[dt];
#pragma unroll
      for (int ks = 0; ks < 2; ++ks) {
        s16x8 vf = *(const s16x8*)&vbuf[dt * 16 + l15][ks * 32 + quad * 8];
        acc = __builtin_amdgcn_mfma_f32_16x16x32_bf16(pf[ks], vf, acc, 0, 0, 0);
      }
      accO[dt] = acc;
    }
  }

  // write unnormalized partials
  float* pOs = pO + (size_t)split * NROWS * 128;
#pragma unroll
  for (int dt = 0; dt < 8; ++dt) {
    int dcol = dt * 16 + l15;
#pragma unroll
    for (int r = 0; r < 4; ++r) {
      int qg = gq0 + w * 16 + quad * 4 + r;
      pOs[(size_t)qg * 128 + dcol] = accO[dt][r];
    }
  }
  if (l15 == 0) {
#pragma unroll
    for (int r = 0; r < 4; ++r) {
      int qg = gq0 + w * 16 + quad * 4 + r;
      pm[split * NROWS + qg] = mstate[r];
      pl[split * NROWS + qg] = lstate[r];
    }
  }
}

// Combine NSPLIT partials: one thread per (row, col).
__global__ __launch_bounds__(256) void attn_reduce_kernel(
    const float* __restrict__ pO, const float* __restrict__ pm,
    const float* __restrict__ pl, unsigned short* __restrict__ O)
{
  const size_t idx = (size_t)blockIdx.x * 256 + threadIdx.x;
  const int row = (int)(idx >> 7);
  float ms[NSPLIT];
  float mstar = NEGF;
#pragma unroll
  for (int s = 0; s < NSPLIT; ++s) {
    ms[s] = pm[s * NROWS + row];
    mstar = fmaxf(mstar, ms[s]);
  }
  float lstar = 0.f, osum = 0.f;
#pragma unroll
  for (int s = 0; s < NSPLIT; ++s) {
    float wgt = __expf(ms[s] - mstar);
    lstar += wgt * pl[s * NROWS + row];
    osum  += wgt * pO[(size_t)s * NROWS * 128 + idx];
  }
  O[idx] = f2bf((lstar > 0.f) ? osum / lstar : 0.f);
}

extern "C" void kernel_launch(void* const* d_in, const int* in_sizes, int n_in,
                              void* d_out, int out_size, void* d_ws, size_t ws_size,
                              hipStream_t stream)
{
  const float* h    = (const float*)d_in[0];
  const float* adj  = (const float*)d_in[1];
  const float* vae2 = (const float*)d_in[2];
  const float* Wv1  = (const float*)d_in[3];
  const float* bv1  = (const float*)d_in[4];
  const float* Wk1  = (const float*)d_in[5];
  const float* bk1  = (const float*)d_in[6];
  const float* Wq1  = (const float*)d_in[7];
  const float* bq1  = (const float*)d_in[8];
  const float* Wo1  = (const float*)d_in[9];
  const float* bo1  = (const float*)d_in[10];
  const float* Wv2  = (const float*)d_in[11];
  const float* bv2  = (const float*)d_in[12];
  const float* Wk2  = (const float*)d_in[13];
  const float* bk2  = (const float*)d_in[14];
  const float* Wq2  = (const float*)d_in[15];
  const float* bq2  = (const float*)d_in[16];
  const float* Wo2  = (const float*)d_in[17];
  const float* bo2  = (const float*)d_in[18];
  const float* Wf   = (const float*)d_in[19];
  const float* bff  = (const float*)d_in[20];

  char* wsb = (char*)d_ws;
  const size_t MB = 1u << 20;
  unsigned short* s_q  = (unsigned short*)(wsb + 0 * MB);
  unsigned short* s_k  = (unsigned short*)(wsb + 4 * MB);
  unsigned short* s_vt = (unsigned short*)(wsb + 8 * MB);
  unsigned short* s_a  = (unsigned short*)(wsb + 12 * MB);
  unsigned short* s_f  = (unsigned short*)(wsb + 16 * MB);
  unsigned short* wbf  = (unsigned short*)(wsb + 20 * MB);
  unsigned long long* maskp = (unsigned long long*)(wsb + 21 * MB);
  float* pO = (float*)(wsb + 25 * MB);                       // 32 MB
  float* pm = (float*)(wsb + 57 * MB);                       // 256 KB
  float* pl = (float*)(wsb + 57 * MB + 512 * 1024);          // 256 KB

  dim3 blk(256);
  conv_w_kernel<<<dim3(128, 18), blk, 0, stream>>>(
      Wq1, Wk1, Wv1, Wo1, Wq2, Wk2, Wv2, Wo2, Wf,
      bq1, bk1, bv1, bo1, bq2, bk2, bv2, bo2, bff, wbf);
  pack_adj_kernel<<<dim3(131072), blk, 0, stream>>>(adj, maskp);

  qkv_kernel<true><<<dim3(1024, 3), blk, 0, stream>>>(
      h, wbf + OW_Q1, wbf + OB_Q1, s_q,
         wbf + OW_K1, wbf + OB_K1, s_k,
         wbf + OW_V1, wbf + OB_V1, s_vt);
  attn_kernel<<<dim3(256, NSPLIT), blk, 0, stream>>>(s_q, s_k, s_vt, maskp, pO, pm, pl);
  attn_reduce_kernel<<<dim3(NROWS * 128 / 256), blk, 0, stream>>>(pO, pm, pl, s_a);
  lin_kernel<<<dim3(1024), blk, 0, stream>>>(s_a, wbf + OW_O1, wbf + OB_O1, s_f);

  qkv_kernel<false><<<dim3(1024, 3), blk, 0, stream>>>(
      s_f, wbf + OW_Q2, wbf + OB_Q2, s_q,
           wbf + OW_K2, wbf + OB_K2, s_k,
           wbf + OW_V2, wbf + OB_V2, s_vt);
  attn_kernel<<<dim3(256, NSPLIT), blk, 0, stream>>>(s_q, s_k, s_vt, maskp, pO, pm, pl);
  attn_reduce_kernel<<<dim3(NROWS * 128 / 256), blk, 0, stream>>>(pO, pm, pl, s_a);
  lin_kernel<<<dim3(1024), blk, 0, stream>>>(s_a, wbf + OW_O2, wbf + OB_O2, s_f);

  final_kernel<<<dim3(1024), blk, 0, stream>>>(
      s_f, wbf + OW_F, vae2, wbf + OB_F, (float*)d_out);
}

// Round 4
// 428.958 us; speedup vs baseline: 1.4242x; 1.1955x over previous
//
#include <hip/hip_runtime.h>

typedef short s16x8 __attribute__((ext_vector_type(8)));
typedef float f32x4 __attribute__((ext_vector_type(4)));
typedef unsigned short u16x4v __attribute__((ext_vector_type(4)));

#define NEGF (-1e30f)
#define NSPLIT 4
#define NROWS 16384   // B*N

__device__ __forceinline__ float bf2f(unsigned short u) {
  union { unsigned int i; float f; } v; v.i = ((unsigned int)u) << 16; return v.f;
}
__device__ __forceinline__ unsigned short f2bf(float f) {
  union { float fl; unsigned int i; } v; v.fl = f;
  unsigned int x = v.i;
  x += 0x7fffu + ((x >> 16) & 1u);   // round-to-nearest-even
  return (unsigned short)(x >> 16);
}
__device__ __forceinline__ s16x8 load8_bf16(const unsigned short* p) {
  return *(const s16x8*)p;
}
__device__ __forceinline__ s16x8 load8_f32(const float* p) {
  float4 a = *(const float4*)p;
  float4 b = *(const float4*)(p + 4);
  s16x8 r;
  r[0] = (short)f2bf(a.x); r[1] = (short)f2bf(a.y);
  r[2] = (short)f2bf(a.z); r[3] = (short)f2bf(a.w);
  r[4] = (short)f2bf(b.x); r[5] = (short)f2bf(b.y);
  r[6] = (short)f2bf(b.z); r[7] = (short)f2bf(b.w);
  return r;
}

// ---------------------------------------------------------------------------
// Weight/bias f32 -> bf16 into workspace (element offsets).
// ---------------------------------------------------------------------------
#define OW_Q1 0
#define OW_K1 16384
#define OW_V1 32768
#define OW_O1 49152
#define OW_Q2 65536
#define OW_K2 81920
#define OW_V2 98304
#define OW_O2 114688
#define OW_F  131072        // 128x256
#define OB_Q1 163840
#define OB_K1 163968
#define OB_V1 164096
#define OB_O1 164224
#define OB_Q2 164352
#define OB_K2 164480
#define OB_V2 164608
#define OB_O2 164736
#define OB_F  164864

__global__ __launch_bounds__(256) void conv_w_kernel(
    const float* s0, const float* s1, const float* s2, const float* s3,
    const float* s4, const float* s5, const float* s6, const float* s7,
    const float* s8, const float* s9, const float* s10, const float* s11,
    const float* s12, const float* s13, const float* s14, const float* s15,
    const float* s16, const float* s17, unsigned short* dst)
{
  const float* src; int count; int off;
  switch (blockIdx.y) {
    case 0:  src = s0;  count = 16384; off = OW_Q1; break;
    case 1:  src = s1;  count = 16384; off = OW_K1; break;
    case 2:  src = s2;  count = 16384; off = OW_V1; break;
    case 3:  src = s3;  count = 16384; off = OW_O1; break;
    case 4:  src = s4;  count = 16384; off = OW_Q2; break;
    case 5:  src = s5;  count = 16384; off = OW_K2; break;
    case 6:  src = s6;  count = 16384; off = OW_V2; break;
    case 7:  src = s7;  count = 16384; off = OW_O2; break;
    case 8:  src = s8;  count = 32768; off = OW_F;  break;
    case 9:  src = s9;  count = 128;   off = OB_Q1; break;
    case 10: src = s10; count = 128;   off = OB_K1; break;
    case 11: src = s11; count = 128;   off = OB_V1; break;
    case 12: src = s12; count = 128;   off = OB_O1; break;
    case 13: src = s13; count = 128;   off = OB_Q2; break;
    case 14: src = s14; count = 128;   off = OB_K2; break;
    case 15: src = s15; count = 128;   off = OB_V2; break;
    case 16: src = s16; count = 128;   off = OB_O2; break;
    default: src = s17; count = 128;   off = OB_F;  break;
  }
  for (int i = blockIdx.x * 256 + threadIdx.x; i < count; i += gridDim.x * 256)
    dst[off + i] = f2bf(src[i]);
}

// ---------------------------------------------------------------------------
// adj -> u64 bitmask. Grid-stride: 8192 wgs (avoid 131072-wg dispatch tax).
// ---------------------------------------------------------------------------
__global__ __launch_bounds__(256) void pack_adj_kernel(
    const float* __restrict__ adj, unsigned long long* __restrict__ mask)
{
  const size_t stride = (size_t)gridDim.x * 256;
  const size_t total = (size_t)NROWS * 2048;
  for (size_t i = (size_t)blockIdx.x * 256 + threadIdx.x; i < total; i += stride) {
    unsigned long long m = __ballot(adj[i] != 0.0f);
    if ((threadIdx.x & 63) == 0) mask[i >> 6] = m;
  }
}

// ---------------------------------------------------------------------------
// NT GEMM (qkv only): wg = 16 rows x 128 cols; wave w owns cols [w*32,+32).
// MODE 0: bf16 rowmajor; MODE 1: bf16 transposed (V^T).
// ---------------------------------------------------------------------------
template <bool A1F32, int MODE>
__device__ __forceinline__ void gemm_body(
    const void* __restrict__ A1, const unsigned short* __restrict__ W1,
    const unsigned short* __restrict__ bias, unsigned short* __restrict__ out)
{
  const int t = threadIdx.x;
  const int w = t >> 6;
  const int lane = t & 63;
  const int l15 = lane & 15;
  const int quad = lane >> 4;
  const int mbase = blockIdx.x * 16;

  s16x8 a1[4];
  if (A1F32) {
    const float* ar = (const float*)A1 + (size_t)(mbase + l15) * 128;
#pragma unroll
    for (int ks = 0; ks < 4; ++ks) a1[ks] = load8_f32(ar + ks * 32 + quad * 8);
  } else {
    const unsigned short* ar = (const unsigned short*)A1 + (size_t)(mbase + l15) * 128;
#pragma unroll
    for (int ks = 0; ks < 4; ++ks) a1[ks] = load8_bf16(ar + ks * 32 + quad * 8);
  }

#pragma unroll
  for (int nt = 0; nt < 2; ++nt) {
    const int n = (w * 2 + nt) * 16 + l15;
    f32x4 acc = {0.f, 0.f, 0.f, 0.f};
    const unsigned short* wr = W1 + (size_t)n * 128;
#pragma unroll
    for (int ks = 0; ks < 4; ++ks)
      acc = __builtin_amdgcn_mfma_f32_16x16x32_bf16(
          a1[ks], load8_bf16(wr + ks * 32 + quad * 8), acc, 0, 0, 0);
    const float bv = bf2f(bias[n]);
    if (MODE == 0) {
#pragma unroll
      for (int r = 0; r < 4; ++r) {
        float v = fmaxf(acc[r] + bv, 0.f);   // relu
        // C layout: row = quad*4+r, col = n  [m89-verified]
        out[(size_t)(mbase + quad * 4 + r) * 128 + n] = f2bf(v);
      }
    } else {
      const int b  = mbase >> 11;
      const int nn = (mbase & 2047) + quad * 4;
      u16x4v pk;
#pragma unroll
      for (int r = 0; r < 4; ++r) pk[r] = f2bf(fmaxf(acc[r] + bv, 0.f));
      *(u16x4v*)(out + (size_t)(b * 128 + n) * 2048 + nn) = pk;
    }
  }
}

template <bool A1F32>
__global__ __launch_bounds__(256) void qkv_kernel(
    const void* __restrict__ x,
    const unsigned short* __restrict__ Wq, const unsigned short* __restrict__ bq, unsigned short* __restrict__ oq,
    const unsigned short* __restrict__ Wk, const unsigned short* __restrict__ bk, unsigned short* __restrict__ ok,
    const unsigned short* __restrict__ Wv, const unsigned short* __restrict__ bv, unsigned short* __restrict__ ovt)
{
  if (blockIdx.y == 0)      gemm_body<A1F32, 0>(x, Wq, bq, oq);
  else if (blockIdx.y == 1) gemm_body<A1F32, 0>(x, Wk, bk, ok);
  else                      gemm_body<A1F32, 1>(x, Wv, bv, ovt);
}

// ---------------------------------------------------------------------------
// Split-K flash attention, 32 q-rows/wave (2 m-tiles share each B-fragment),
// wg = 128 q-rows, register prefetch of next K/V chunk.
// grid = (128 row-blocks, NSPLIT).
// ---------------------------------------------------------------------------
__global__ __launch_bounds__(256, 2) void attn_kernel(
    const unsigned short* __restrict__ Q,
    const unsigned short* __restrict__ K,
    const unsigned short* __restrict__ VT,
    const unsigned long long* __restrict__ MASK,
    float* __restrict__ pO, float* __restrict__ pm, float* __restrict__ pl)
{
  __shared__ __align__(16) unsigned short kbuf[64][136];
  __shared__ __align__(16) unsigned short vbuf[128][72];
  __shared__ __align__(16) unsigned short pbuf[4][32][72];

  const int t = threadIdx.x;
  const int w = t >> 6;
  const int lane = t & 63;
  const int l15 = lane & 15;
  const int quad = lane >> 4;

  const int gq0 = blockIdx.x * 128;
  const int b   = gq0 >> 11;
  const int q0  = gq0 & 2047;
  const int wq0 = q0 + w * 32;
  const int kc0 = blockIdx.y * 512;
  const int kc1 = kc0 + 512;

  const unsigned short* Kb  = K  + (size_t)(b * 2048) * 128;
  const unsigned short* VTb = VT + (size_t)(b * 128) * 2048;
  const unsigned long long* Mb = MASK + (size_t)b * 2048 * 32;

  s16x8 qf[2][4];
#pragma unroll
  for (int mt = 0; mt < 2; ++mt) {
    const unsigned short* qrow = Q + (size_t)(gq0 + w * 32 + mt * 16 + l15) * 128;
#pragma unroll
    for (int ks = 0; ks < 4; ++ks) qf[mt][ks] = load8_bf16(qrow + ks * 32 + quad * 8);
  }

  float mstate[2][4], lstate[2][4];
  f32x4 accO[2][8];
#pragma unroll
  for (int mt = 0; mt < 2; ++mt) {
#pragma unroll
    for (int r = 0; r < 4; ++r) { mstate[mt][r] = NEGF; lstate[mt][r] = 0.f; }
#pragma unroll
    for (int dt = 0; dt < 8; ++dt) accO[mt][dt] = (f32x4){0.f, 0.f, 0.f, 0.f};
  }

  // prefetch first chunk into registers
  s16x8 kr[4], vr[4];
#pragma unroll
  for (int i = 0; i < 4; ++i) {
    int slot = i * 256 + t;
    kr[i] = load8_bf16(Kb + (size_t)(kc0 + (slot >> 4)) * 128 + (slot & 15) * 8);
    vr[i] = load8_bf16(VTb + (size_t)(slot >> 3) * 2048 + kc0 + (slot & 7) * 8);
  }

  for (int kc = kc0; kc < kc1; kc += 64) {
    __syncthreads();   // prior chunk's LDS reads complete
#pragma unroll
    for (int i = 0; i < 4; ++i) {
      int slot = i * 256 + t;
      *(s16x8*)&kbuf[slot >> 4][(slot & 15) * 8] = kr[i];
      *(s16x8*)&vbuf[slot >> 3][(slot & 7) * 8]  = vr[i];
    }
    __syncthreads();
    if (kc + 64 < kc1) {
#pragma unroll
      for (int i = 0; i < 4; ++i) {
        int slot = i * 256 + t;
        kr[i] = load8_bf16(Kb + (size_t)(kc + 64 + (slot >> 4)) * 128 + (slot & 15) * 8);
        vr[i] = load8_bf16(VTb + (size_t)(slot >> 3) * 2048 + (kc + 64) + (slot & 7) * 8);
      }
    }

    // S = Q * K^T, two 16-row m-tiles share each K fragment
    f32x4 sv[2][4];
#pragma unroll
    for (int nt = 0; nt < 4; ++nt) {
      sv[0][nt] = (f32x4){0.f, 0.f, 0.f, 0.f};
      sv[1][nt] = (f32x4){0.f, 0.f, 0.f, 0.f};
#pragma unroll
      for (int ks = 0; ks < 4; ++ks) {
        s16x8 kf = *(const s16x8*)&kbuf[nt * 16 + l15][ks * 32 + quad * 8];
        sv[0][nt] = __builtin_amdgcn_mfma_f32_16x16x32_bf16(qf[0][ks], kf, sv[0][nt], 0, 0, 0);
        sv[1][nt] = __builtin_amdgcn_mfma_f32_16x16x32_bf16(qf[1][ks], kf, sv[1][nt], 0, 0, 0);
      }
    }

    // mask + row max
    float chmax[2][4];
#pragma unroll
    for (int mt = 0; mt < 2; ++mt) {
#pragma unroll
      for (int r = 0; r < 4; ++r) {
        unsigned long long mw = Mb[(size_t)(wq0 + mt * 16 + quad * 4 + r) * 32 + (kc >> 6)];
        float cm = NEGF;
#pragma unroll
        for (int nt = 0; nt < 4; ++nt) {
          float s = ((mw >> (nt * 16 + l15)) & 1ull) ? sv[mt][nt][r] : NEGF;
          sv[mt][nt][r] = s;
          cm = fmaxf(cm, s);
        }
        chmax[mt][r] = cm;
      }
    }
#pragma unroll
    for (int d = 1; d < 16; d <<= 1) {
#pragma unroll
      for (int mt = 0; mt < 2; ++mt)
#pragma unroll
        for (int r = 0; r < 4; ++r)
          chmax[mt][r] = fmaxf(chmax[mt][r], __shfl_xor(chmax[mt][r], d, 64));
    }

    float mnew[2][4], alpha[2][4], rsum[2][4];
#pragma unroll
    for (int mt = 0; mt < 2; ++mt)
#pragma unroll
      for (int r = 0; r < 4; ++r) {
        mnew[mt][r] = fmaxf(mstate[mt][r], chmax[mt][r]);
        alpha[mt][r] = __expf(mstate[mt][r] - mnew[mt][r]);
        rsum[mt][r] = 0.f;
      }
#pragma unroll
    for (int mt = 0; mt < 2; ++mt)
#pragma unroll
      for (int nt = 0; nt < 4; ++nt)
#pragma unroll
        for (int r = 0; r < 4; ++r) {
          float p = __expf(sv[mt][nt][r] - mnew[mt][r]);
          rsum[mt][r] += p;
          pbuf[w][mt * 16 + quad * 4 + r][nt * 16 + l15] = f2bf(p);
        }
#pragma unroll
    for (int d = 1; d < 16; d <<= 1) {
#pragma unroll
      for (int mt = 0; mt < 2; ++mt)
#pragma unroll
        for (int r = 0; r < 4; ++r)
          rsum[mt][r] += __shfl_xor(rsum[mt][r], d, 64);
    }
#pragma unroll
    for (int mt = 0; mt < 2; ++mt)
#pragma unroll
      for (int r = 0; r < 4; ++r) {
        lstate[mt][r] = lstate[mt][r] * alpha[mt][r] + rsum[mt][r];
        mstate[mt][r] = mnew[mt][r];
      }
#pragma unroll
    for (int mt = 0; mt < 2; ++mt)
#pragma unroll
      for (int dt = 0; dt < 8; ++dt)
#pragma unroll
        for (int r = 0; r < 4; ++r) accO[mt][dt][r] *= alpha[mt][r];

    // pbuf is wave-local; in-wave LDS RAW ordering suffices (no barrier).
    s16x8 pf[2][2];
#pragma unroll
    for (int mt = 0; mt < 2; ++mt)
#pragma unroll
      for (int ks = 0; ks < 2; ++ks)
        pf[mt][ks] = *(const s16x8*)&pbuf[w][mt * 16 + l15][ks * 32 + quad * 8];
#pragma unroll
    for (int dt = 0; dt < 8; ++dt) {
#pragma unroll
      for (int ks = 0; ks < 2; ++ks) {
        s16x8 vf = *(const s16x8*)&vbuf[dt * 16 + l15][ks * 32 + quad * 8];
        accO[0][dt] = __builtin_amdgcn_mfma_f32_16x16x32_bf16(pf[0][ks], vf, accO[0][dt], 0, 0, 0);
        accO[1][dt] = __builtin_amdgcn_mfma_f32_16x16x32_bf16(pf[1][ks], vf, accO[1][dt], 0, 0, 0);
      }
    }
  }

  float* pOs = pO + (size_t)blockIdx.y * NROWS * 128;
#pragma unroll
  for (int mt = 0; mt < 2; ++mt)
#pragma unroll
    for (int dt = 0; dt < 8; ++dt) {
      int dcol = dt * 16 + l15;
#pragma unroll
      for (int r = 0; r < 4; ++r) {
        int qg = gq0 + w * 32 + mt * 16 + quad * 4 + r;
        pOs[(size_t)qg * 128 + dcol] = accO[mt][dt][r];
      }
    }
  if (l15 == 0) {
#pragma unroll
    for (int mt = 0; mt < 2; ++mt)
#pragma unroll
      for (int r = 0; r < 4; ++r) {
        int qg = gq0 + w * 32 + mt * 16 + quad * 4 + r;
        pm[blockIdx.y * NROWS + qg] = mstate[mt][r];
        pl[blockIdx.y * NROWS + qg] = lstate[mt][r];
      }
  }
}

// ---------------------------------------------------------------------------
// Fused split-K reduce + O-projection (+ optional final concat-GEMM).
// wg = 16 rows; grid = 1024.
// ---------------------------------------------------------------------------
template <bool FINAL>
__global__ __launch_bounds__(256) void red_lin_kernel(
    const float* __restrict__ pO, const float* __restrict__ pm,
    const float* __restrict__ pl,
    const unsigned short* __restrict__ Wo, const unsigned short* __restrict__ bo,
    const unsigned short* __restrict__ Wf, const float* __restrict__ vae2,
    const unsigned short* __restrict__ bfb,
    unsigned short* __restrict__ out_bf, float* __restrict__ out_f32)
{
  __shared__ __align__(16) unsigned short At[16][136];
  __shared__ __align__(16) unsigned short Bt[16][136];

  const int t = threadIdx.x;
  const int grow0 = blockIdx.x * 16;

  // Phase A: combine splits -> normalized attention rows (bf16) in LDS
  {
    const int row = t >> 4;
    const int col8 = (t & 15) * 8;
    const int grow = grow0 + row;
    float ms[NSPLIT], mstar = NEGF;
#pragma unroll
    for (int s = 0; s < NSPLIT; ++s) {
      ms[s] = pm[s * NROWS + grow];
      mstar = fmaxf(mstar, ms[s]);
    }
    float wgt[NSPLIT], lstar = 0.f;
#pragma unroll
    for (int s = 0; s < NSPLIT; ++s) {
      wgt[s] = __expf(ms[s] - mstar);
      lstar += wgt[s] * pl[s * NROWS + grow];
    }
    const float inv = (lstar > 0.f) ? 1.f / lstar : 0.f;
    float acc8[8];
#pragma unroll
    for (int i = 0; i < 8; ++i) acc8[i] = 0.f;
#pragma unroll
    for (int s = 0; s < NSPLIT; ++s) {
      const float* p = pO + (size_t)s * NROWS * 128 + (size_t)grow * 128 + col8;
      float4 x0 = *(const float4*)p;
      float4 x1 = *(const float4*)(p + 4);
      acc8[0] += wgt[s] * x0.x; acc8[1] += wgt[s] * x0.y;
      acc8[2] += wgt[s] * x0.z; acc8[3] += wgt[s] * x0.w;
      acc8[4] += wgt[s] * x1.x; acc8[5] += wgt[s] * x1.y;
      acc8[6] += wgt[s] * x1.z; acc8[7] += wgt[s] * x1.w;
    }
#pragma unroll
    for (int i = 0; i < 8; ++i) At[row][col8 + i] = f2bf(acc8[i] * inv);
  }
  __syncthreads();

  const int w = t >> 6;
  const int lane = t & 63;
  const int l15 = lane & 15;
  const int quad = lane >> 4;

  // Phase B: tile @ Wo^T + bo
  s16x8 a[4];
#pragma unroll
  for (int ks = 0; ks < 4; ++ks) a[ks] = *(const s16x8*)&At[l15][ks * 32 + quad * 8];
#pragma unroll
  for (int nt = 0; nt < 2; ++nt) {
    const int n = (w * 2 + nt) * 16 + l15;
    f32x4 acc = {0.f, 0.f, 0.f, 0.f};
    const unsigned short* wr = Wo + (size_t)n * 128;
#pragma unroll
    for (int ks = 0; ks < 4; ++ks)
      acc = __builtin_amdgcn_mfma_f32_16x16x32_bf16(
          a[ks], load8_bf16(wr + ks * 32 + quad * 8), acc, 0, 0, 0);
    const float bv = bf2f(bo[n]);
    if (!FINAL) {
#pragma unroll
      for (int r = 0; r < 4; ++r)
        out_bf[(size_t)(grow0 + quad * 4 + r) * 128 + n] = f2bf(acc[r] + bv);
    } else {
#pragma unroll
      for (int r = 0; r < 4; ++r)
        Bt[quad * 4 + r][n] = f2bf(acc[r] + bv);
    }
  }

  if (FINAL) {
    __syncthreads();
    // Phase C: out = Bt @ WfL^T + vae2 @ WfR^T + bf  (f32 out)
    s16x8 a1[4], a2[4];
#pragma unroll
    for (int ks = 0; ks < 4; ++ks) a1[ks] = *(const s16x8*)&Bt[l15][ks * 32 + quad * 8];
    const float* vrow = vae2 + (size_t)(grow0 + l15) * 128;
#pragma unroll
    for (int ks = 0; ks < 4; ++ks) a2[ks] = load8_f32(vrow + ks * 32 + quad * 8);
#pragma unroll
    for (int nt = 0; nt < 2; ++nt) {
      const int n = (w * 2 + nt) * 16 + l15;
      f32x4 acc = {0.f, 0.f, 0.f, 0.f};
      const unsigned short* wr = Wf + (size_t)n * 256;
#pragma unroll
      for (int ks = 0; ks < 4; ++ks)
        acc = __builtin_amdgcn_mfma_f32_16x16x32_bf16(
            a1[ks], load8_bf16(wr + ks * 32 + quad * 8), acc, 0, 0, 0);
#pragma unroll
      for (int ks = 0; ks < 4; ++ks)
        acc = __builtin_amdgcn_mfma_f32_16x16x32_bf16(
            a2[ks], load8_bf16(wr + 128 + ks * 32 + quad * 8), acc, 0, 0, 0);
      const float bv = bf2f(bfb[n]);
#pragma unroll
      for (int r = 0; r < 4; ++r)
        out_f32[(size_t)(grow0 + quad * 4 + r) * 128 + n] = acc[r] + bv;
    }
  }
}

extern "C" void kernel_launch(void* const* d_in, const int* in_sizes, int n_in,
                              void* d_out, int out_size, void* d_ws, size_t ws_size,
                              hipStream_t stream)
{
  const float* h    = (const float*)d_in[0];
  const float* adj  = (const float*)d_in[1];
  const float* vae2 = (const float*)d_in[2];
  const float* Wv1  = (const float*)d_in[3];
  const float* bv1  = (const float*)d_in[4];
  const float* Wk1  = (const float*)d_in[5];
  const float* bk1  = (const float*)d_in[6];
  const float* Wq1  = (const float*)d_in[7];
  const float* bq1  = (const float*)d_in[8];
  const float* Wo1  = (const float*)d_in[9];
  const float* bo1  = (const float*)d_in[10];
  const float* Wv2  = (const float*)d_in[11];
  const float* bv2  = (const float*)d_in[12];
  const float* Wk2  = (const float*)d_in[13];
  const float* bk2  = (const float*)d_in[14];
  const float* Wq2  = (const float*)d_in[15];
  const float* bq2  = (const float*)d_in[16];
  const float* Wo2  = (const float*)d_in[17];
  const float* bo2  = (const float*)d_in[18];
  const float* Wf   = (const float*)d_in[19];
  const float* bff  = (const float*)d_in[20];

  char* wsb = (char*)d_ws;
  const size_t MB = 1u << 20;
  unsigned short* s_q  = (unsigned short*)(wsb + 0 * MB);
  unsigned short* s_k  = (unsigned short*)(wsb + 4 * MB);
  unsigned short* s_vt = (unsigned short*)(wsb + 8 * MB);
  unsigned short* s_f  = (unsigned short*)(wsb + 12 * MB);
  unsigned short* wbf  = (unsigned short*)(wsb + 16 * MB);
  unsigned long long* maskp = (unsigned long long*)(wsb + 17 * MB);
  float* pO = (float*)(wsb + 21 * MB);                       // 32 MB
  float* pm = (float*)(wsb + 53 * MB);                       // 256 KB
  float* pl = (float*)(wsb + 53 * MB + 512 * 1024);          // 256 KB

  dim3 blk(256);
  conv_w_kernel<<<dim3(128, 18), blk, 0, stream>>>(
      Wq1, Wk1, Wv1, Wo1, Wq2, Wk2, Wv2, Wo2, Wf,
      bq1, bk1, bv1, bo1, bq2, bk2, bv2, bo2, bff, wbf);
  pack_adj_kernel<<<dim3(8192), blk, 0, stream>>>(adj, maskp);

  qkv_kernel<true><<<dim3(1024, 3), blk, 0, stream>>>(
      h, wbf + OW_Q1, wbf + OB_Q1, s_q,
         wbf + OW_K1, wbf + OB_K1, s_k,
         wbf + OW_V1, wbf + OB_V1, s_vt);
  attn_kernel<<<dim3(128, NSPLIT), blk, 0, stream>>>(s_q, s_k, s_vt, maskp, pO, pm, pl);
  red_lin_kernel<false><<<dim3(1024), blk, 0, stream>>>(
      pO, pm, pl, wbf + OW_O1, wbf + OB_O1, nullptr, nullptr, nullptr, s_f, nullptr);

  qkv_kernel<false><<<dim3(1024, 3), blk, 0, stream>>>(
      s_f, wbf + OW_Q2, wbf + OB_Q2, s_q,
           wbf + OW_K2, wbf + OB_K2, s_k,
           wbf + OW_V2, wbf + OB_V2, s_vt);
  attn_kernel<<<dim3(128, NSPLIT), blk, 0, stream>>>(s_q, s_k, s_vt, maskp, pO, pm, pl);
  red_lin_kernel<true><<<dim3(1024), blk, 0, stream>>>(
      pO, pm, pl, wbf + OW_O2, wbf + OB_O2, wbf + OW_F, vae2, wbf + OB_F,
      nullptr, (float*)d_out);
}